// Round 3
// baseline (2114.925 us; speedup 1.0000x reference)
//
#include <hip/hip_runtime.h>

typedef float f32x4 __attribute__((ext_vector_type(4)));
typedef _Float16 f16x8 __attribute__((ext_vector_type(8)));
typedef _Float16 f16x2 __attribute__((ext_vector_type(2)));

typedef __attribute__((address_space(1))) const unsigned char gbyte;
typedef __attribute__((address_space(3))) unsigned char sbyte;
__device__ __forceinline__ void gload_lds16(const void* gp, void* lp) {
  __builtin_amdgcn_global_load_lds((gbyte*)gp, (sbyte*)lp, 16, 0, 0);
}

// ---------------- 1. weight-pool transpose to [d][o][i], f32 ----------------
__global__ __launch_bounds__(256) void k_wpoolT(const float* __restrict__ gwp,
                                                const float* __restrict__ uwp,
                                                float* __restrict__ wtg,
                                                float* __restrict__ wtu) {
  int idx = blockIdx.x * 256 + threadIdx.x;
  if (idx < 16 * 128 * 128) {
    int d = idx >> 14, rem = idx & 16383, o = rem >> 7, i = rem & 127;
    wtg[idx] = gwp[(d << 14) + (i << 7) + o];          // gwp[d][i][o]
  } else {
    int j = idx - 16 * 128 * 128;
    if (j < 16 * 64 * 128) {
      int d = j >> 13, rem = j & 8191, o = rem >> 7, i = rem & 127;
      wtu[j] = uwp[(d << 13) + (i << 6) + o];          // uwp[d][i][o(64)]
    }
  }
}

// ---------------- 2. supports = softmax(relu(E E^T)) row-wise, f16 ----------
__global__ __launch_bounds__(256) void k_supports(const float* __restrict__ emb,
                                                  _Float16* __restrict__ S) {
  int n = blockIdx.x, tid = threadIdx.x;
  float en[16];
#pragma unroll
  for (int d = 0; d < 16; d++) en[d] = emb[n * 16 + d];
  float v[16];
  float sum = 0.f;
#pragma unroll
  for (int i = 0; i < 16; i++) {
    int m = i * 256 + tid;
    const float* em = emb + m * 16;
    float acc = 0.f;
#pragma unroll
    for (int d = 0; d < 16; d++) acc += en[d] * em[d];
    acc = fmaxf(acc, 0.f);
    float e = __expf(acc);   // relu'd logit <= ~55 -> finite in f32
    v[i] = e;
    sum += e;
  }
#pragma unroll
  for (int off = 32; off > 0; off >>= 1) sum += __shfl_down(sum, off);
  __shared__ float red[4];
  if ((tid & 63) == 0) red[tid >> 6] = sum;
  __syncthreads();
  float inv = 1.f / (red[0] + red[1] + red[2] + red[3]);
#pragma unroll
  for (int i = 0; i < 16; i++) S[n * 4096 + i * 256 + tid] = (_Float16)(v[i] * inv);
}

// ------- 3. xs_t[b][c][m] = f16(concat(x,state))  (c-major for GEMM B) ------
__global__ __launch_bounds__(256) void k_concat(const float* __restrict__ x,
                                                const float* __restrict__ st,
                                                _Float16* __restrict__ xs_t) {
  int m0 = blockIdx.x * 64, b = blockIdx.y, tid = threadIdx.x;
  __shared__ __attribute__((aligned(16))) _Float16 T[64][130];
#pragma unroll
  for (int i = 0; i < 16; i++) {
    int li = i * 256 + tid;
    int ml = li >> 6, c = li & 63;
    int base = (b * 4096 + m0 + ml) * 64 + c;
    T[ml][c] = (_Float16)x[base];
    T[ml][64 + c] = (_Float16)st[base];
  }
  __syncthreads();
  int cg = tid >> 3, mch = tid & 7;
#pragma unroll
  for (int cb = 0; cb < 4; cb++) {
    int c = cb * 32 + cg;
    f16x8 tmp;
#pragma unroll
    for (int j = 0; j < 8; j++) tmp[j] = T[mch * 8 + j][c];
    *reinterpret_cast<f16x8*>(&xs_t[(b * 128 + c) * 4096 + m0 + mch * 8]) = tmp;
  }
}

// -------- 4. Y[b][n][c] = sum_m S[n][m] * xs_t[b][c][m]  (f16 MFMA) ---------
__global__ __launch_bounds__(256) void k_gemm(const _Float16* __restrict__ S,
                                              const _Float16* __restrict__ Xt,
                                              _Float16* __restrict__ Y) {
  int nt = blockIdx.x, b = blockIdx.y;
  int tid = threadIdx.x, lane = tid & 63, w = tid >> 6;
  int wr = w >> 1, wc = w & 1;
  __shared__ __attribute__((aligned(16))) _Float16 As[128 * 64];
  __shared__ __attribute__((aligned(16))) _Float16 Bs[128 * 64];
  const _Float16* Sb = S + nt * 128 * 4096;
  const _Float16* Xb = Xt + b * 128 * 4096;
  f32x4 acc[4][4];
#pragma unroll
  for (int m = 0; m < 4; m++)
#pragma unroll
    for (int n = 0; n < 4; n++) acc[m][n] = (f32x4){0.f, 0.f, 0.f, 0.f};

  int lrow = lane >> 3;          // 0..7
  int lcol = (lane & 7) * 8;     // f16-element offset (16B per lane)
  for (int k0 = 0; k0 < 4096; k0 += 64) {
    __syncthreads();
#pragma unroll
    for (int i = 0; i < 4; i++) {
      int j = w * 4 + i;
      int row = j * 8 + lrow;
      gload_lds16(Sb + row * 4096 + k0 + lcol, &As[j * 512]);
      gload_lds16(Xb + row * 4096 + k0 + lcol, &Bs[j * 512]);
    }
    __syncthreads();
#pragma unroll
    for (int kk = 0; kk < 2; kk++) {
      f16x8 af[4], bfr[4];
#pragma unroll
      for (int m = 0; m < 4; m++)
        af[m] = *reinterpret_cast<const f16x8*>(
            &As[(wr * 64 + m * 16 + (lane & 15)) * 64 + kk * 32 + (lane >> 4) * 8]);
#pragma unroll
      for (int n = 0; n < 4; n++)
        bfr[n] = *reinterpret_cast<const f16x8*>(
            &Bs[(wc * 64 + n * 16 + (lane & 15)) * 64 + kk * 32 + (lane >> 4) * 8]);
#pragma unroll
      for (int m = 0; m < 4; m++)
#pragma unroll
        for (int n = 0; n < 4; n++)
          acc[m][n] = __builtin_amdgcn_mfma_f32_16x16x32_f16(af[m], bfr[n], acc[m][n], 0, 0, 0);
    }
  }
  int r0 = (lane >> 4) * 4, cl = lane & 15;
#pragma unroll
  for (int m = 0; m < 4; m++)
#pragma unroll
    for (int r = 0; r < 4; r++) {
      int row = nt * 128 + wr * 64 + m * 16 + r0 + r;
#pragma unroll
      for (int n = 0; n < 4; n++) {
        int c = wc * 64 + n * 16 + cl;
        Y[(b * 4096 + row) * 128 + c] = (_Float16)acc[m][n][r];
      }
    }
}

// -------- 5. gate (f32 VALU): z_r = sigmoid(x_g @ W_n + b_n) -> zb, rb ------
__global__ __launch_bounds__(256) void k_gate(const _Float16* __restrict__ xg,  // [b][n][128]
                                              const float* __restrict__ emb,
                                              const float* __restrict__ wtg,    // [16][128][128]
                                              const float* __restrict__ gbp,    // [16][128]
                                              _Float16* __restrict__ zb,        // [n][b][64]
                                              _Float16* __restrict__ rb) {      // [n][b][64]
  int n = blockIdx.x, tid = threadIdx.x, lane = tid & 63, og = tid >> 6;
  __shared__ _Float16 A[64][130];    // [b][i], pad->conflict-free per-lane reads
  __shared__ _Float16 W[128][128];   // [o][i], broadcast reads
  __shared__ float bias_sh[128];
  __shared__ float e_sh[16];
  if (tid < 16) e_sh[tid] = emb[n * 16 + tid];
  __syncthreads();
  // stage A: thread t -> row b=t>>2, i-range (t&3)*32..+31
  {
    int b = tid >> 2, i0 = (tid & 3) * 32;
    const f16x8* s8 = reinterpret_cast<const f16x8*>(xg + (b * 4096 + n) * 128 + i0);
#pragma unroll
    for (int c = 0; c < 4; c++) {
      f16x8 v = s8[c];
#pragma unroll
      for (int j = 0; j < 8; j++) A[b][i0 + c * 8 + j] = v[j];
    }
  }
  // stage W: W[o][i] = sum_d e_d * wtg[d][o][i] (f32 acc -> f16)
  {
    int o = tid >> 1, ih = tid & 1;
#pragma unroll
    for (int c8 = 0; c8 < 8; c8++) {
      int i0 = ih * 64 + c8 * 8;
      f32x4 a0 = {0.f, 0.f, 0.f, 0.f}, a1 = {0.f, 0.f, 0.f, 0.f};
#pragma unroll
      for (int d = 0; d < 16; d++) {
        float e = e_sh[d];
        const f32x4* p = reinterpret_cast<const f32x4*>(&wtg[(d * 128 + o) * 128 + i0]);
        a0 += e * p[0];
        a1 += e * p[1];
      }
#pragma unroll
      for (int q = 0; q < 4; q++) {
        W[o][i0 + q] = (_Float16)a0[q];
        W[o][i0 + 4 + q] = (_Float16)a1[q];
      }
    }
  }
  if (tid < 128) {
    float s = 0.f;
#pragma unroll
    for (int d = 0; d < 16; d++) s += e_sh[d] * gbp[d * 128 + tid];
    bias_sh[tid] = s;
  }
  __syncthreads();
  // compute: b = lane, o = og*32 + oi (32 outputs/thread), f32 acc
  float acc[32];
#pragma unroll
  for (int oi = 0; oi < 32; oi++) acc[oi] = bias_sh[og * 32 + oi];
  for (int i = 0; i < 128; i += 2) {
    f16x2 a2 = *reinterpret_cast<const f16x2*>(&A[lane][i]);
    float a0 = (float)a2[0], a1 = (float)a2[1];
#pragma unroll
    for (int oi = 0; oi < 32; oi++) {
      f16x2 w2 = *reinterpret_cast<const f16x2*>(&W[og * 32 + oi][i]);
      acc[oi] += a0 * (float)w2[0] + a1 * (float)w2[1];
    }
  }
#pragma unroll
  for (int oi = 0; oi < 32; oi++) {
    int o = og * 32 + oi;
    float sg = 1.f / (1.f + __expf(-acc[oi]));
    if (o < 64) zb[(n * 64 + lane) * 64 + o] = (_Float16)sg;
    else        rb[(n * 64 + lane) * 64 + (o - 64)] = (_Float16)sg;
  }
}

// ------------- 6. xs_t[b][64+o][m] = f16(z[m][b][o] * state[b][m][o]) -------
__global__ __launch_bounds__(256) void k_cand(const _Float16* __restrict__ zb,
                                              const float* __restrict__ st,
                                              _Float16* __restrict__ xs_t) {
  int m0 = blockIdx.x * 64, b = blockIdx.y, tid = threadIdx.x;
  __shared__ __attribute__((aligned(16))) _Float16 T[64][66];
#pragma unroll
  for (int i = 0; i < 16; i++) {
    int li = i * 256 + tid, ml = li >> 6, o = li & 63;
    float z = (float)zb[((m0 + ml) * 64 + b) * 64 + o];
    float s = st[(b * 4096 + m0 + ml) * 64 + o];
    T[ml][o] = (_Float16)(z * s);
  }
  __syncthreads();
  int og = tid >> 3, mch = tid & 7;
#pragma unroll
  for (int cb = 0; cb < 2; cb++) {
    int o = cb * 32 + og;
    f16x8 tmp;
#pragma unroll
    for (int j = 0; j < 8; j++) tmp[j] = T[mch * 8 + j][o];
    *reinterpret_cast<f16x8*>(&xs_t[(b * 128 + 64 + o) * 4096 + m0 + mch * 8]) = tmp;
  }
}

// ---- 7. update (f32 VALU): hc=tanh(xg2 @ Wu_n + bu); h=r*s+(1-r)*hc -> out -
__global__ __launch_bounds__(256) void k_upd(const _Float16* __restrict__ xg2,  // [b][n][128]
                                             const float* __restrict__ emb,
                                             const float* __restrict__ wtu,    // [16][64][128]
                                             const float* __restrict__ ubp,    // [16][64]
                                             const _Float16* __restrict__ rb,  // [n][b][64]
                                             const float* __restrict__ st,
                                             float* __restrict__ out) {
  int n = blockIdx.x, tid = threadIdx.x, lane = tid & 63, og = tid >> 6;
  __shared__ _Float16 A[64][130];
  __shared__ _Float16 W[64][128];
  __shared__ float bias_sh[64];
  __shared__ float e_sh[16];
  if (tid < 16) e_sh[tid] = emb[n * 16 + tid];
  __syncthreads();
  {
    int b = tid >> 2, i0 = (tid & 3) * 32;
    const f16x8* s8 = reinterpret_cast<const f16x8*>(xg2 + (b * 4096 + n) * 128 + i0);
#pragma unroll
    for (int c = 0; c < 4; c++) {
      f16x8 v = s8[c];
#pragma unroll
      for (int j = 0; j < 8; j++) A[b][i0 + c * 8 + j] = v[j];
    }
  }
  {
    int o = tid >> 2, q = tid & 3;
#pragma unroll
    for (int c8 = 0; c8 < 4; c8++) {
      int i0 = q * 32 + c8 * 8;
      f32x4 a0 = {0.f, 0.f, 0.f, 0.f}, a1 = {0.f, 0.f, 0.f, 0.f};
#pragma unroll
      for (int d = 0; d < 16; d++) {
        float e = e_sh[d];
        const f32x4* p = reinterpret_cast<const f32x4*>(&wtu[(d * 64 + o) * 128 + i0]);
        a0 += e * p[0];
        a1 += e * p[1];
      }
#pragma unroll
      for (int q2 = 0; q2 < 4; q2++) {
        W[o][i0 + q2] = (_Float16)a0[q2];
        W[o][i0 + 4 + q2] = (_Float16)a1[q2];
      }
    }
  }
  if (tid < 64) {
    float s = 0.f;
#pragma unroll
    for (int d = 0; d < 16; d++) s += e_sh[d] * ubp[d * 64 + tid];
    bias_sh[tid] = s;
  }
  __syncthreads();
  // compute: b = lane, o = og*16 + oi (16 outputs/thread)
  float acc[16];
#pragma unroll
  for (int oi = 0; oi < 16; oi++) acc[oi] = bias_sh[og * 16 + oi];
  for (int i = 0; i < 128; i += 2) {
    f16x2 a2 = *reinterpret_cast<const f16x2*>(&A[lane][i]);
    float a0 = (float)a2[0], a1 = (float)a2[1];
#pragma unroll
    for (int oi = 0; oi < 16; oi++) {
      f16x2 w2 = *reinterpret_cast<const f16x2*>(&W[og * 16 + oi][i]);
      acc[oi] += a0 * (float)w2[0] + a1 * (float)w2[1];
    }
  }
#pragma unroll
  for (int oi = 0; oi < 16; oi++) {
    int o = og * 16 + oi;
    float e2 = __expf(2.f * acc[oi]);
    float hc = 1.f - 2.f / (e2 + 1.f);     // tanh
    float rr = (float)rb[(n * 64 + lane) * 64 + o];
    float s = st[(lane * 4096 + n) * 64 + o];
    out[(lane * 4096 + n) * 64 + o] = rr * s + (1.f - rr) * hc;
  }
}

extern "C" void kernel_launch(void* const* d_in, const int* in_sizes, int n_in,
                              void* d_out, int out_size, void* d_ws, size_t ws_size,
                              hipStream_t stream) {
  const float* x   = (const float*)d_in[0];
  const float* st  = (const float*)d_in[1];
  const float* emb = (const float*)d_in[2];
  const float* gwp = (const float*)d_in[3];
  const float* gbp = (const float*)d_in[4];
  const float* uwp = (const float*)d_in[5];
  const float* ubp = (const float*)d_in[6];
  float* out = (float*)d_out;
  char* ws = (char*)d_ws;

  // round-1 proven buffer timeline, all f16:
  _Float16* S    = (_Float16*)(ws + 0);          // 33.5 MB (alive throughout)
  _Float16* xs_t = (_Float16*)(ws + 33554432);   // 67 MB [b][c][m]
  _Float16* xg   = (_Float16*)(ws + 100663296);  // 67 MB (gemm1 out; gemm2 overwrites)
  _Float16* zb   = (_Float16*)(ws + 167772160);  // 33.5 MB [n][b][64]
  _Float16* rb   = (_Float16*)(ws + 201326592);  // 33.5 MB [n][b][64]
  float* wtg = (float*)(ws + 234881024);         // 1 MB
  float* wtu = (float*)(ws + 235929600);         // 0.5 MB
  if (ws_size < 236453888ull) return;  // fail loudly rather than corrupt

  k_wpoolT<<<1536, 256, 0, stream>>>(gwp, uwp, wtg, wtu);
  k_supports<<<4096, 256, 0, stream>>>(emb, S);
  k_concat<<<dim3(64, 64), 256, 0, stream>>>(x, st, xs_t);
  k_gemm<<<dim3(32, 64), 256, 0, stream>>>(S, xs_t, xg);
  k_gate<<<4096, 256, 0, stream>>>(xg, emb, wtg, gbp, zb, rb);
  k_cand<<<dim3(64, 64), 256, 0, stream>>>(zb, st, xs_t);
  k_gemm<<<dim3(32, 64), 256, 0, stream>>>(S, xs_t, xg);
  k_upd<<<4096, 256, 0, stream>>>(xg, emb, wtu, ubp, rb, st, out);
}